// Round 2
// baseline (213.798 us; speedup 1.0000x reference)
//
#include <hip/hip_runtime.h>

#define BLOCK 256
#define GRID 2048

typedef float floatx4 __attribute__((ext_vector_type(4)));
typedef int   intx4   __attribute__((ext_vector_type(4)));

__device__ __forceinline__ float row_loss(floatx4 x, int t, const float* sw) {
    // argmax, first-occurrence tie-break (strictly-greater scan)
    float best = x.x; int pred = 0;
    if (x.y > best) { best = x.y; pred = 1; }
    if (x.z > best) { best = x.z; pred = 2; }
    if (x.w > best) { best = x.w; pred = 3; }
    const float sev = sw[t * 4 + pred];
    // native-rate transcendentals: v_exp_f32 / v_log_f32
    const float s = __expf(x.x - best) + __expf(x.y - best) +
                    __expf(x.z - best) + __expf(x.w - best);
    const float lse = best + __logf(s);
    const float xt = (t == 0) ? x.x : (t == 1) ? x.y : (t == 2) ? x.z : x.w;
    return sev + (lse - xt);
}

// Each thread owns 4 CONSECUTIVE rows per iteration:
//   - 4x global_load_dwordx4 at immediate offsets 0/16/32/48 off ONE address
//   - 1x global_load_dwordx4 fetching all 4 int32 targets
// => 5 VMEM per 4 rows (was 8), ~4x less 64-bit address arithmetic.
// Plain (cached) loads — the 6.3 TB/s streaming ceiling was measured with
// plain loads; nt gives no reuse benefit here and is the untested variable.
__global__ __launch_bounds__(BLOCK, 8) void wcl_main_kernel(
    const float* __restrict__ out,      // [B*4] logits
    const int*   __restrict__ tgt,      // [B] targets (0..3)
    const float* __restrict__ w,        // [16] severity weights
    float*       __restrict__ partials, // [GRID] per-block sums
    int B)
{
    __shared__ float sw[16];
    __shared__ float wave_sums[BLOCK / 64];

    if (threadIdx.x < 16) sw[threadIdx.x] = w[threadIdx.x];
    __syncthreads();

    const int nG = B >> 2;                 // groups of 4 rows
    const int gstride = GRID * BLOCK;      // group-stride
    int g = blockIdx.x * BLOCK + threadIdx.x;

    float local = 0.0f;
    for (; g < nG; g += gstride) {
        const floatx4* xrow = (const floatx4*)out + 4 * (size_t)g; // 64B contiguous
        floatx4 x0 = xrow[0];
        floatx4 x1 = xrow[1];
        floatx4 x2 = xrow[2];
        floatx4 x3 = xrow[3];
        intx4 t4 = *(const intx4*)(tgt + 4 * (size_t)g);
        local += row_loss(x0, t4.x, sw);
        local += row_loss(x1, t4.y, sw);
        local += row_loss(x2, t4.z, sw);
        local += row_loss(x3, t4.w, sw);
    }

    // tail: rows [nG*4, B) if B not divisible by 4 (not hit for B=8388608)
    if (blockIdx.x == 0) {
        const int rem = B & 3;
        if ((int)threadIdx.x < rem) {
            const int r = (nG << 2) + threadIdx.x;
            floatx4 x = ((const floatx4*)out)[r];
            local += row_loss(x, tgt[r], sw);
        }
    }

    // wave-64 shuffle reduction
    #pragma unroll
    for (int off = 32; off > 0; off >>= 1)
        local += __shfl_down(local, off);

    const int lane = threadIdx.x & 63;
    const int wave = threadIdx.x >> 6;
    if (lane == 0) wave_sums[wave] = local;
    __syncthreads();

    if (threadIdx.x == 0) {
        float bsum = 0.0f;
        #pragma unroll
        for (int j = 0; j < BLOCK / 64; ++j) bsum += wave_sums[j];
        partials[blockIdx.x] = bsum;
    }
}

__global__ __launch_bounds__(BLOCK) void wcl_final_kernel(
    const float* __restrict__ partials, float* __restrict__ out, int B)
{
    __shared__ double wave_sums[BLOCK / 64];
    double local = 0.0;
    for (int i = threadIdx.x; i < GRID; i += BLOCK)
        local += (double)partials[i];

    #pragma unroll
    for (int off = 32; off > 0; off >>= 1)
        local += __shfl_down(local, off);

    const int lane = threadIdx.x & 63;
    const int wave = threadIdx.x >> 6;
    if (lane == 0) wave_sums[wave] = local;
    __syncthreads();

    if (threadIdx.x == 0) {
        double s = 0.0;
        #pragma unroll
        for (int j = 0; j < BLOCK / 64; ++j) s += wave_sums[j];
        out[0] = (float)(s / (double)B);
    }
}

extern "C" void kernel_launch(void* const* d_in, const int* in_sizes, int n_in,
                              void* d_out, int out_size, void* d_ws, size_t ws_size,
                              hipStream_t stream) {
    const float* outputs = (const float*)d_in[0];   // [B,4] fp32
    const int*   targets = (const int*)d_in[1];     // [B] int32
    const float* weights = (const float*)d_in[2];   // [4,4] fp32
    const int B = in_sizes[0] / 4;

    float* partials = (float*)d_ws;                 // GRID floats

    wcl_main_kernel<<<GRID, BLOCK, 0, stream>>>(
        outputs, targets, weights, partials, B);
    wcl_final_kernel<<<1, BLOCK, 0, stream>>>(partials, (float*)d_out, B);
}

// Round 3
// 206.016 us; speedup vs baseline: 1.0378x; 1.0378x over previous
//
#include <hip/hip_runtime.h>
#include <hip/hip_bf16.h>

#define BLOCK 256
#define GRID 2048

typedef float floatx4 __attribute__((ext_vector_type(4)));

__device__ __forceinline__ float row_loss(floatx4 x, int t, const float* sw) {
    // argmax, first-occurrence tie-break (strictly-greater scan)
    float best = x.x; int pred = 0;
    if (x.y > best) { best = x.y; pred = 1; }
    if (x.z > best) { best = x.z; pred = 2; }
    if (x.w > best) { best = x.w; pred = 3; }
    const float sev = sw[t * 4 + pred];
    // native-rate transcendentals: v_exp_f32 / v_log_f32
    const float s = __expf(x.x - best) + __expf(x.y - best) +
                    __expf(x.z - best) + __expf(x.w - best);
    const float lse = best + __logf(s);
    const float xt = (t == 0) ? x.x : (t == 1) ? x.y : (t == 2) ? x.z : x.w;
    return sev + (lse - xt);
}

// Proven-best structure (R0, 204.4 us; prior session 204.5 us):
//  - nontemporal loads (streaming reads stay out of the cache path the
//    harness's 512 MB fills are hammering; both best runs had NT, the
//    non-NT variant regressed)
//  - lane-contiguous grid-stride: lane i -> out4[base+i], 1 KiB/wave/instr,
//    4 KiB wave footprint (R2's 64 B/lane layout regressed)
//  - plain launch bounds (the (256,8) cap was neutral -> already <=64 VGPR)
__global__ __launch_bounds__(BLOCK) void wcl_main_kernel(
    const floatx4* __restrict__ out4,     // [B] rows of 4 logits
    const int*     __restrict__ tgt,      // [B] targets (0..3)
    const float*   __restrict__ w,        // [16] severity weights
    float*         __restrict__ partials, // [GRID] per-block sums
    int B)
{
    __shared__ float sw[16];
    __shared__ float wave_sums[BLOCK / 64];

    if (threadIdx.x < 16) sw[threadIdx.x] = w[threadIdx.x];
    __syncthreads();

    const int stride = GRID * BLOCK;
    int i = blockIdx.x * BLOCK + threadIdx.x;

    float local = 0.0f;
    while (i + 3 * stride < B) {
        floatx4 x0 = __builtin_nontemporal_load(&out4[i]);
        floatx4 x1 = __builtin_nontemporal_load(&out4[i + stride]);
        floatx4 x2 = __builtin_nontemporal_load(&out4[i + 2 * stride]);
        floatx4 x3 = __builtin_nontemporal_load(&out4[i + 3 * stride]);
        int t0 = __builtin_nontemporal_load(&tgt[i]);
        int t1 = __builtin_nontemporal_load(&tgt[i + stride]);
        int t2 = __builtin_nontemporal_load(&tgt[i + 2 * stride]);
        int t3 = __builtin_nontemporal_load(&tgt[i + 3 * stride]);
        local += row_loss(x0, t0, sw);
        local += row_loss(x1, t1, sw);
        local += row_loss(x2, t2, sw);
        local += row_loss(x3, t3, sw);
        i += 4 * stride;
    }
    while (i < B) {
        floatx4 x = __builtin_nontemporal_load(&out4[i]);
        int t = __builtin_nontemporal_load(&tgt[i]);
        local += row_loss(x, t, sw);
        i += stride;
    }

    // wave-64 shuffle reduction
    #pragma unroll
    for (int off = 32; off > 0; off >>= 1)
        local += __shfl_down(local, off);

    const int lane = threadIdx.x & 63;
    const int wave = threadIdx.x >> 6;
    if (lane == 0) wave_sums[wave] = local;
    __syncthreads();

    if (threadIdx.x == 0) {
        float bsum = 0.0f;
        #pragma unroll
        for (int j = 0; j < BLOCK / 64; ++j) bsum += wave_sums[j];
        partials[blockIdx.x] = bsum;
    }
}

__global__ __launch_bounds__(BLOCK) void wcl_final_kernel(
    const float* __restrict__ partials, float* __restrict__ out, int B)
{
    __shared__ double wave_sums[BLOCK / 64];
    double local = 0.0;
    for (int i = threadIdx.x; i < GRID; i += BLOCK)
        local += (double)partials[i];

    #pragma unroll
    for (int off = 32; off > 0; off >>= 1)
        local += __shfl_down(local, off);

    const int lane = threadIdx.x & 63;
    const int wave = threadIdx.x >> 6;
    if (lane == 0) wave_sums[wave] = local;
    __syncthreads();

    if (threadIdx.x == 0) {
        double s = 0.0;
        #pragma unroll
        for (int j = 0; j < BLOCK / 64; ++j) s += wave_sums[j];
        out[0] = (float)(s / (double)B);
    }
}

extern "C" void kernel_launch(void* const* d_in, const int* in_sizes, int n_in,
                              void* d_out, int out_size, void* d_ws, size_t ws_size,
                              hipStream_t stream) {
    const float* outputs = (const float*)d_in[0];   // [B,4] fp32
    const int*   targets = (const int*)d_in[1];     // [B] int32
    const float* weights = (const float*)d_in[2];   // [4,4] fp32
    const int B = in_sizes[0] / 4;

    float* partials = (float*)d_ws;                 // GRID floats

    wcl_main_kernel<<<GRID, BLOCK, 0, stream>>>(
        (const floatx4*)outputs, targets, weights, partials, B);
    wcl_final_kernel<<<1, BLOCK, 0, stream>>>(partials, (float*)d_out, B);
}